// Round 3
// baseline (40.789 us; speedup 1.0000x reference)
//
#include <hip/hip_runtime.h>

#define N_ATOMS 512
#define N_PAIRS 130816            // 512*511/2
#define BATCH 128
#define PAIRS_PER_BLOCK 1024      // 256 threads x 4 pairs (lane-strided)
#define BLOCKS_PER_BATCH 128      // ceil(130816 / 1024)

typedef float f32x4 __attribute__((ext_vector_type(4)));

// AU2KCALMOLA / MAX_NRF
constexpr float SCALE = (float)(627.5095 * 0.529177 / 100.0);

// Row index i (>=1) such that i*(i-1)/2 <= p < i*(i+1)/2.
__device__ __forceinline__ int row_of_pair(int p) {
    float fp = (float)p;
    int i = (int)((1.0f + sqrtf(1.0f + 8.0f * fp)) * 0.5f);
    if ((i * (i - 1)) / 2 > p) --i;
    else if ((i * (i + 1)) / 2 <= p) ++i;
    return i;
}

__global__ __launch_bounds__(256) void coords_to_nrf_kernel(
    const float* __restrict__ coords,   // [B, 512, 3]
    const float* __restrict__ atom_nc,  // [B, N_PAIRS]
    float* __restrict__ out)            // [B, N_PAIRS]
{
    __shared__ float c[N_ATOMS * 3];    // 6144 B

    const int b = blockIdx.y;
    const int t = threadIdx.x;

    // Stage this batch's coords into LDS (coalesced f32x4; source is L2-resident).
    {
        const f32x4* src = reinterpret_cast<const f32x4*>(coords + (size_t)b * (N_ATOMS * 3));
        f32x4* dst = reinterpret_cast<f32x4*>(c);
        #pragma unroll
        for (int u = t; u < (N_ATOMS * 3) / 4; u += 256) dst[u] = src[u];
    }
    __syncthreads();

    const int seg = blockIdx.x * PAIRS_PER_BLOCK;
    const float* anc = atom_nc + (size_t)b * N_PAIRS;
    float* ob = out + (size_t)b * N_PAIRS;

    // Hoist the streaming loads so HBM latency overlaps the LDS/VALU work.
    float a[4];
    int   pp[4];
    #pragma unroll
    for (int k = 0; k < 4; ++k) {
        pp[k] = seg + k * 256 + t;
        a[k] = (pp[k] < N_PAIRS) ? __builtin_nontemporal_load(&anc[pp[k]]) : 0.0f;
    }

    #pragma unroll
    for (int k = 0; k < 4; ++k) {
        int p = pp[k];
        if (p < N_PAIRS) {
            int i = row_of_pair(p);
            int j = p - (i * (i - 1)) / 2;
            // i is wave-uniform (broadcast); j has lane-stride 3 floats ->
            // bank stride 3 (coprime with 32) -> conflict-free ds_read_b32.
            float xi = c[3 * i], yi = c[3 * i + 1], zi = c[3 * i + 2];
            float xj = c[3 * j], yj = c[3 * j + 1], zj = c[3 * j + 2];
            float dx = xi - xj, dy = yi - yj, dz = zi - zj;
            float d2 = dx * dx + dy * dy + dz * dz;
            __builtin_nontemporal_store(a[k] * (SCALE / d2), &ob[p]);
        }
    }
}

extern "C" void kernel_launch(void* const* d_in, const int* in_sizes, int n_in,
                              void* d_out, int out_size, void* d_ws, size_t ws_size,
                              hipStream_t stream) {
    const float* coords  = (const float*)d_in[0];  // [128, 512, 3] f32
    const float* atom_nc = (const float*)d_in[1];  // [128, 130816] f32
    float* out = (float*)d_out;                    // [128, 130816] f32

    dim3 block(256);
    dim3 grid(BLOCKS_PER_BATCH, BATCH);            // 128 x 128 blocks
    coords_to_nrf_kernel<<<grid, block, 0, stream>>>(coords, atom_nc, out);
}